// Round 13
// baseline (92.626 us; speedup 1.0000x reference)
//
#include <hip/hip_runtime.h>
#include <hip/hip_bf16.h>

// 3D conv K=2 VALID + (y+1)^2, mfma_f32_32x32x16_bf16, vectorized streams.
// x: (8,16,64,64,64) f32; w: (32,128) f32, k = c*8 + kd*4 + kh*2 + kw.
// out: (8,32,63,63,63) f32.
//
// R12 (76.8 us) + ONE change: the strip-based LDS transpose (18 b64 writes
// + 72 scalar u16 reads + 18 b64 writes per thread) is replaced by a
// register-block transpose: staging thread (hsub, cq, wqlow) loads 4x
// dwordx4 from 4 consecutive c-planes at one (h, 4w) quad (still 16 B/lane
// global), transposes the 4c x 4w block in registers (free - pack order in
// the cvt), and writes 4x u16x4 directly to the tile. Staging LDS ops drop
// 108 -> 18 per thread; strip buffer gone.
//   tile [p][h][w][c16] u16, h-stride 1040 (16-u16 pad): pad makes BOTH
//   staging b64 writes (16 bank-pair starts x hsub/cq) and fragment b128
//   reads (32 banks, 8/bank = min) exactly conflict-free.
//   Load order keeps R11's T14 burst under the 128-VGPR/4-wave budget:
//   issue 4 main rounds (64 regs) -> drain 0,1 -> issue h=8 tails -> drain
//   2,3 -> tails. Compute + line-aligned hybrid NT drain = R12 identical.

typedef __attribute__((ext_vector_type(8)))  short short8;
typedef __attribute__((ext_vector_type(4)))  float f32x4;
typedef __attribute__((ext_vector_type(16))) float f32x16;
typedef __attribute__((ext_vector_type(4)))  unsigned short u16x4;

#define XCS 262144        // 64^3 x channel stride (f32)
#define OS  250047        // 63^3 out channel stride (f32)
#define HST 1040          // tile h-stride in u16 (64w*16c + 16 pad)
#define PST 9360          // tile p(kd)-stride in u16 (9 * HST)
#define IMG_DW 536        // dwords per epilogue run slot (504 + 32 line pad)

__device__ __forceinline__ unsigned short f2bf(float f) {
    unsigned int u = __builtin_bit_cast(unsigned int, f);
    return (unsigned short)((u + 0x7fffu + ((u >> 16) & 1u)) >> 16);
}

__global__ __launch_bounds__(256, 4) void conv3d_k2_regT(
    const float* __restrict__ x,
    const float* __restrict__ wgt,
    float* __restrict__ out)
{
    __shared__ __align__(16) unsigned char lds_raw[37440];
    unsigned short* tile = (unsigned short*)lds_raw;   // [2][9][64][c16] u16 (+pad)
    float* img = (float*)lds_raw;                      // [16][536] f32 (epilogue)

    const int t   = threadIdx.x;
    const int l   = t & 63;
    const int wv  = t >> 6;        // wave 0..3
    const int col = l & 31;        // MFMA col (w) / A row (o)
    const int kh8 = l >> 5;        // k-half -> c8 group

    const int h0 = blockIdx.x * 8; // 8 output h rows
    const int d  = blockIdx.y;     // 0..62
    const int b  = blockIdx.z;

    // ---- A fragments: 64 contiguous floats per lane, compile-time shuffle ----
    short8 aF[8];
    {
        f32x4 wreg[16];
        const float* wp = wgt + col * 128 + kh8 * 64;
#pragma unroll
        for (int q = 0; q < 16; ++q) wreg[q] = *(const f32x4*)(wp + q * 4);
#pragma unroll
        for (int tap = 0; tap < 8; ++tap) {
            short8 a;
#pragma unroll
            for (int j = 0; j < 8; ++j) {
                const int k = j * 8 + tap;
                a[j] = (short)f2bf(wreg[k >> 2][k & 3]);
            }
            aF[tap] = a;
        }
    }

    // ---- staging: 4-c-plane dwordx4 loads + register-block transpose ----
    // lane roles: hsub = l>>4, cq = (l>>2)&3, wq = wv*4 + (l&3)
    const int hsub = l >> 4;
    const int scq  = (l >> 2) & 3;
    const int wq   = wv * 4 + (l & 3);
    const float* xb = x + (size_t)b * 16 * XCS;

    // main rounds rd = (p<<1)|hq : h = h0 + hq*4 + hsub (<= 63 always)
    f32x4 v[4][4];
#pragma unroll
    for (int rd = 0; rd < 4; ++rd) {
        const int p  = rd >> 1;
        const int hq = rd & 1;
        const float* xs = xb + (size_t)(d + p) * 4096
                             + (h0 + hq * 4 + hsub) * 64 + wq * 4;
#pragma unroll
        for (int i = 0; i < 4; ++i)
            v[rd][i] = *(const f32x4*)(xs + (size_t)(scq * 4 + i) * XCS);
    }

    // drain rounds 0,1 (register 4x4 transpose -> direct tile writes)
#pragma unroll
    for (int rd = 0; rd < 2; ++rd) {
        const int p = rd >> 1, hq = rd & 1, h = hq * 4 + hsub;
#pragma unroll
        for (int i = 0; i < 4; ++i) {
            u16x4 pk;
#pragma unroll
            for (int j = 0; j < 4; ++j) pk[j] = f2bf(v[rd][j][i]);
            *(u16x4*)&tile[p * PST + h * HST + (wq * 4 + i) * 16 + scq * 4] = pk;
        }
    }

    // tail loads: h = h0+8 (clamped), hsub==0 lanes only
    f32x4 vt[2][4];
    int hp8 = h0 + 8; if (hp8 > 63) hp8 = 63;
    if (hsub == 0) {
#pragma unroll
        for (int p = 0; p < 2; ++p) {
            const float* xs = xb + (size_t)(d + p) * 4096 + hp8 * 64 + wq * 4;
#pragma unroll
            for (int i = 0; i < 4; ++i)
                vt[p][i] = *(const f32x4*)(xs + (size_t)(scq * 4 + i) * XCS);
        }
    }

    // drain rounds 2,3
#pragma unroll
    for (int rd = 2; rd < 4; ++rd) {
        const int p = rd >> 1, hq = rd & 1, h = hq * 4 + hsub;
#pragma unroll
        for (int i = 0; i < 4; ++i) {
            u16x4 pk;
#pragma unroll
            for (int j = 0; j < 4; ++j) pk[j] = f2bf(v[rd][j][i]);
            *(u16x4*)&tile[p * PST + h * HST + (wq * 4 + i) * 16 + scq * 4] = pk;
        }
    }

    // drain tails
    if (hsub == 0) {
#pragma unroll
        for (int p = 0; p < 2; ++p)
#pragma unroll
            for (int i = 0; i < 4; ++i) {
                u16x4 pk;
#pragma unroll
                for (int j = 0; j < 4; ++j) pk[j] = f2bf(vt[p][j][i]);
                *(u16x4*)&tile[p * PST + 8 * HST + (wq * 4 + i) * 16 + scq * 4] = pk;
            }
    }
    __syncthreads();

    // ---- compute: 4 acc tiles (2 h-rows x 2 w-halves) kept in regs ----
    f32x16 acc[2][2];
#pragma unroll
    for (int th = 0; th < 2; ++th) {
        const int hl = wv * 2 + th;
#pragma unroll
        for (int wh = 0; wh < 2; ++wh) {
            const int wb = wh * 32;
            f32x16 a = {};
#pragma unroll
            for (int kd = 0; kd < 2; ++kd)
#pragma unroll
            for (int kh = 0; kh < 2; ++kh)
#pragma unroll
            for (int kw = 0; kw < 2; ++kw) {
                const int tap = kd * 4 + kh * 2 + kw;
                short8 bfrag = *(const short8*)&tile[kd * PST
                    + (hl + kh) * HST + (wb + col + kw) * 16 + kh8 * 8];
                a = __builtin_amdgcn_mfma_f32_32x32x16_bf16(aF[tap], bfrag, a, 0, 0, 0);
            }
            acc[th][wh] = a;
        }
    }
    __syncthreads();   // done reading tile; LDS becomes the store image

    // ---- epilogue: 2 passes x 16 o-runs, line-aligned hybrid drain ----
    const int hvalid = (h0 == 56) ? 7 : 8;
    const int runlen = hvalid * 63;
#pragma unroll
    for (int p = 0; p < 2; ++p) {
        // scatter (y+1)^2 into img, shifted by each run's base&31 (128-B line)
#pragma unroll
        for (int th = 0; th < 2; ++th) {
            const int hl = wv * 2 + th;
            if (hl < hvalid) {
#pragma unroll
                for (int wh = 0; wh < 2; ++wh) {
                    const int wc = wh * 32 + col;
                    if (wc < 63) {
#pragma unroll
                        for (int r = 0; r < 8; ++r) {
                            const int rr = p * 8 + r;
                            const int og = (rr & 3) + 8 * (rr >> 2) + 4 * kh8;
                            const int ol = og - p * 16;
                            // base_dw mod 32: OS=-1, 3969=+1, 63=-1 (mod 32)
                            const int sh = (int)(((unsigned)(d - og - h0 + 1024)) & 31u);
                            float y = acc[th][wh][rr] + 1.0f;
                            img[ol * IMG_DW + sh + hl * 63 + wc] = y * y;
                        }
                    }
                }
            }
        }
        __syncthreads();
        // drain: wave wv owns 4 runs; cached fringes + NT line-aligned interior
#pragma unroll
        for (int orun = 0; orun < 4; ++orun) {
            const int ol = wv * 4 + orun;
            const int og = p * 16 + ol;
            const size_t base_dw = ((size_t)b * 32 + og) * (size_t)OS
                                 + (size_t)d * 3969 + (size_t)h0 * 63;
            float* gp = out + base_dw;
            const int sh = (int)(base_dw & 31);
            const float* ip = img + ol * IMG_DW + sh;
            int hc = (32 - sh) & 31;                 // head dwords (cached)
            if (hc > runlen) hc = runlen;
            if (l < hc) gp[l] = ip[l];
            const int ni = ((runlen - hc) >> 5) << 5; // interior (full 128-B lines)
            const int nv = ni >> 2;                   // x4 NT stores
#pragma unroll
            for (int rnd = 0; rnd < 2; ++rnd) {
                const int k = rnd * 64 + l;
                if (k < nv) {
                    f32x4 qv = *(const f32x4*)(ip + hc + 4 * k);
                    __builtin_nontemporal_store(qv, (f32x4*)(gp + hc + 4 * k));
                }
            }
            const int ts = hc + ni;                   // tail fringe (cached)
            if (ts + l < runlen) gp[ts + l] = ip[ts + l];
        }
        if (p == 0) __syncthreads();   // img reused by pass-1 scatter
    }
}

extern "C" void kernel_launch(void* const* d_in, const int* in_sizes, int n_in,
                              void* d_out, int out_size, void* d_ws, size_t ws_size,
                              hipStream_t stream) {
    const float* x   = (const float*)d_in[0];
    const float* wgt = (const float*)d_in[1];
    float* out = (float*)d_out;

    dim3 grid(8, 63, 8);    // h-tiles, d, b (linear = L2-friendly map)
    dim3 block(256);
    conv3d_k2_regT<<<grid, block, 0, stream>>>(x, wgt, out);
}

// Round 14
// 77.277 us; speedup vs baseline: 1.1986x; 1.1986x over previous
//
#include <hip/hip_runtime.h>
#include <hip/hip_bf16.h>

// 3D conv K=2 VALID + (y+1)^2, mfma_f32_32x32x16_bf16, d-rolling + vectorized
// streams. x: (8,16,64,64,64) f32; w: (32,128) f32, k = c*8+kd*4+kh*2+kw.
// out: (8,32,63,63,63) f32.
//
// R12 (76.8 us anchor) + ND=4 d-rolling at 2 blocks/CU:
//  - block owns (b, 8 h-rows, 4 d): stages 5 slabs per 4 outputs (was 2 per
//    1: logical reads -36%), weights/A-frags once per 4 d, barriers 4/d.
//  - T14 prefetch: slab d+2's 9 dwordx4 issued before compute, consumed
//    (strip-transpose -> LDS) after the epilogue drain (R11-proven).
//  - img gets its own LDS region (no tile overlay): post-compute barrier
//    gone. LDS = tile 36,864 + strip 4,096 + img 34,304 = 75,264 B.
//  - staging/compute/epilogue byte-identical to R12: strip transpose with
//    16-B/lane loads, conflict-free [kd][kh8][9h][64w][8c] tile, 32 MFMA,
//    line-aligned hybrid NT drain.

typedef __attribute__((ext_vector_type(8)))  short short8;
typedef __attribute__((ext_vector_type(4)))  float f32x4;
typedef __attribute__((ext_vector_type(16))) float f32x16;
typedef __attribute__((ext_vector_type(4)))  unsigned short u16x4;

#define XCS 262144        // 64^3 x channel stride (f32)
#define OS  250047        // 63^3 out channel stride (f32)
#define SLAB_E 9216       // u16 per kd slab: [2 kh8][9 h][64 w][8 c]
#define KH8_E  4608       // 9*64*8
#define IMG_DW 536        // dwords per epilogue run slot (504 + 32 line pad)

__device__ __forceinline__ unsigned short f2bf(float f) {
    unsigned int u = __builtin_bit_cast(unsigned int, f);
    return (unsigned short)((u + 0x7fffu + ((u >> 16) & 1u)) >> 16);
}

__global__ __launch_bounds__(256, 2) void conv3d_k2_rollvec(
    const float* __restrict__ x,
    const float* __restrict__ wgt,
    float* __restrict__ out)
{
    __shared__ __align__(16) unsigned char lds_raw[75264];
    unsigned short* tile  = (unsigned short*)lds_raw;            // [2][2][9][64][8] u16
    unsigned short* strip = (unsigned short*)(lds_raw + 36864);  // [2][16c][64w] u16
    float* img = (float*)(lds_raw + 40960);                      // [16][536] f32

    const int t   = threadIdx.x;
    const int l   = t & 63;
    const int wv  = t >> 6;        // wave 0..3
    const int col = l & 31;        // MFMA col (w) / A row (o)
    const int kh8 = l >> 5;        // k-half -> c8 group

    const int h0 = blockIdx.x * 8; // 8 output h rows
    const int d0 = blockIdx.y * 4; // 4 output d (3 in last chunk)
    const int b  = blockIdx.z;
    const int nd = (d0 == 60) ? 3 : 4;

    // ---- A fragments: 64 contiguous floats per lane, compile-time shuffle ----
    short8 aF[8];
    {
        f32x4 wreg[16];
        const float* wp = wgt + col * 128 + kh8 * 64;
#pragma unroll
        for (int q = 0; q < 16; ++q) wreg[q] = *(const f32x4*)(wp + q * 4);
#pragma unroll
        for (int tap = 0; tap < 8; ++tap) {
            short8 a;
#pragma unroll
            for (int j = 0; j < 8; ++j) {
                const int k = j * 8 + tap;
                a[j] = (short)f2bf(wreg[k >> 2][k & 3]);
            }
            aF[tap] = a;
        }
    }

    // ---- staging lane roles (R12): cA = c-plane, wq = 16-B w quad ----
    const int cA   = t >> 4;
    const int wq   = t & 15;
    const int wB   = l;
    const int kh8s = wv >> 1;
    const int half = wv & 1;
    const float* xb = x + (size_t)b * 16 * XCS + (size_t)cA * XCS + wq * 4;

    // strip transpose: regs (one slab, 9 h-rows) -> tile buffer bufSel
    auto xpose = [&](const f32x4* vv, int bufSel) {
#pragma unroll
        for (int h = 0; h < 9; ++h) {
            unsigned short* sb = strip + (h & 1) * 1024;
            u16x4 pk;
#pragma unroll
            for (int i = 0; i < 4; ++i) pk[i] = f2bf(vv[h][i]);
            *(u16x4*)&sb[cA * 64 + wq * 4] = pk;
            u16x4 q;
#pragma unroll
            for (int i = 0; i < 4; ++i)
                q[i] = sb[(wv * 4 + i) * 64 + wB];
            *(u16x4*)&tile[bufSel * SLAB_E + kh8s * KH8_E + h * 512 + wB * 8 + half * 4] = q;
        }
    };

    // ---- prologue: fused burst of slabs d0, d0+1 -> bufs 0,1 ----
    {
        f32x4 v0[9], v1[9];
#pragma unroll
        for (int h = 0; h < 9; ++h) {
            int hp = h0 + h; if (hp > 63) hp = 63;
            v0[h] = *(const f32x4*)(xb + (size_t)d0 * 4096 + hp * 64);
        }
#pragma unroll
        for (int h = 0; h < 9; ++h) {
            int hp = h0 + h; if (hp > 63) hp = 63;
            v1[h] = *(const f32x4*)(xb + (size_t)(d0 + 1) * 4096 + hp * 64);
        }
        xpose(v0, 0);
        xpose(v1, 1);
    }
    __syncthreads();

    const int hvalid = (h0 == 56) ? 7 : 8;
    const int runlen = hvalid * 63;

    for (int dd = 0; dd < nd; ++dd) {
        const bool doPre = (dd + 1) < nd;

        // T14: issue slab d0+dd+2's loads now; consume after the drain
        f32x4 pre[9];
        if (doPre) {
#pragma unroll
            for (int h = 0; h < 9; ++h) {
                int hp = h0 + h; if (hp > 63) hp = 63;
                pre[h] = *(const f32x4*)(xb + (size_t)(d0 + dd + 2) * 4096 + hp * 64);
            }
        }

        const int pA = (dd & 1) * SLAB_E;        // slab d0+dd   (kd=0)
        const int pB = ((dd + 1) & 1) * SLAB_E;  // slab d0+dd+1 (kd=1)

        // ---- compute: 4 acc tiles (2 h-rows x 2 w-halves) in regs ----
        f32x16 acc[2][2];
#pragma unroll
        for (int th = 0; th < 2; ++th) {
            const int hl = wv * 2 + th;
#pragma unroll
            for (int wh = 0; wh < 2; ++wh) {
                const int wb = wh * 32;
                f32x16 a = {};
#pragma unroll
                for (int kd = 0; kd < 2; ++kd)
#pragma unroll
                for (int kh = 0; kh < 2; ++kh)
#pragma unroll
                for (int kw = 0; kw < 2; ++kw) {
                    const int tap = kd * 4 + kh * 2 + kw;
                    short8 bfrag = *(const short8*)&tile[(kd ? pB : pA)
                        + kh8 * KH8_E + (hl + kh) * 512 + (wb + col + kw) * 8];
                    a = __builtin_amdgcn_mfma_f32_32x32x16_bf16(aF[tap], bfrag, a, 0, 0, 0);
                }
                acc[th][wh] = a;
            }
        }
        // no barrier: img is disjoint from tile; previous drain is fenced
        // by the end-of-iteration barrier.

        // ---- epilogue for d = d0+dd (R12's 2-pass hybrid drain) ----
        const int dcur = d0 + dd;
#pragma unroll
        for (int p = 0; p < 2; ++p) {
#pragma unroll
            for (int th = 0; th < 2; ++th) {
                const int hl = wv * 2 + th;
                if (hl < hvalid) {
#pragma unroll
                    for (int wh = 0; wh < 2; ++wh) {
                        const int wc = wh * 32 + col;
                        if (wc < 63) {
#pragma unroll
                            for (int r = 0; r < 8; ++r) {
                                const int rr = p * 8 + r;
                                const int og = (rr & 3) + 8 * (rr >> 2) + 4 * kh8;
                                const int ol = og - p * 16;
                                // base_dw mod 32: OS=-1, 3969=+1, 63=-1
                                const int sh = (int)(((unsigned)(dcur - og - h0 + 1024)) & 31u);
                                float y = acc[th][wh][rr] + 1.0f;
                                img[ol * IMG_DW + sh + hl * 63 + wc] = y * y;
                            }
                        }
                    }
                }
            }
            __syncthreads();
            // drain: wave wv owns 4 runs; cached fringes + NT aligned interior
#pragma unroll
            for (int orun = 0; orun < 4; ++orun) {
                const int ol = wv * 4 + orun;
                const int og = p * 16 + ol;
                const size_t base_dw = ((size_t)b * 32 + og) * (size_t)OS
                                     + (size_t)dcur * 3969 + (size_t)h0 * 63;
                float* gp = out + base_dw;
                const int sh = (int)(base_dw & 31);
                const float* ip = img + ol * IMG_DW + sh;
                int hc = (32 - sh) & 31;                  // head (cached)
                if (hc > runlen) hc = runlen;
                if (l < hc) gp[l] = ip[l];
                const int ni = ((runlen - hc) >> 5) << 5; // full 128-B lines
                const int nv = ni >> 2;
#pragma unroll
                for (int rnd = 0; rnd < 2; ++rnd) {
                    const int k = rnd * 64 + l;
                    if (k < nv) {
                        f32x4 qv = *(const f32x4*)(ip + hc + 4 * k);
                        __builtin_nontemporal_store(qv, (f32x4*)(gp + hc + 4 * k));
                    }
                }
                const int ts = hc + ni;                   // tail (cached)
                if (ts + l < runlen) gp[ts + l] = ip[ts + l];
            }
            if (p == 0) __syncthreads();   // img reused by pass-1 scatter
        }

        // ---- consume prefetch: slab d0+dd+2 -> buf (dd&1) ----
        if (doPre) xpose(pre, dd & 1);
        __syncthreads();   // tile write visible; img free for next scatter
    }
}

extern "C" void kernel_launch(void* const* d_in, const int* in_sizes, int n_in,
                              void* d_out, int out_size, void* d_ws, size_t ws_size,
                              hipStream_t stream) {
    const float* x   = (const float*)d_in[0];
    const float* wgt = (const float*)d_in[1];
    float* out = (float*)d_out;

    dim3 grid(8, 16, 8);    // h-tiles, d-chunks(4), b
    dim3 block(256);
    conv3d_k2_rollvec<<<grid, block, 0, stream>>>(x, wgt, out);
}

// Round 15
// 74.037 us; speedup vs baseline: 1.2511x; 1.0438x over previous
//
#include <hip/hip_runtime.h>
#include <hip/hip_bf16.h>

// 3D conv K=2 VALID + (y+1)^2, mfma_f32_32x32x16_bf16, vectorized streams.
// x: (8,16,64,64,64) f32; w: (32,128) f32, k = c*8 + kd*4 + kh*2 + kw.
// out: (8,32,63,63,63) f32.
//
// R12 (76.8 us anchor) + ONE change: XCD-partitioned block mapping (T1).
// grid(4032) 1D; decode b = bid&7, ht = (bid>>3)&7, d = bid>>6. Since the
// dispatcher round-robins bids across XCDs, XCD b now owns ALL blocks of
// batch b: d-neighbor slab reuse, h-halo reuse, and the 8 h-tile co-reads
// of each slab all become XCD-local L2 hits (active window ~16 slabs ~4.6MB
// vs 4MB L2). Old map co-located only d-neighbors; same-slab h-tiles
// scattered across all 8 XCDs and re-fetched via L3 per XCD.
//   - staging: 18x dwordx4 fused burst (T14) + strip transpose
//   - tile [2kd][2kh8][9h][64w][8c] bf16, conflict-free b128 fragments
//   - 32 MFMA/wave; line-aligned hybrid NT drain via LDS img
//   - LDS 40960 B = 4 blocks/CU

typedef __attribute__((ext_vector_type(8)))  short short8;
typedef __attribute__((ext_vector_type(4)))  float f32x4;
typedef __attribute__((ext_vector_type(16))) float f32x16;
typedef __attribute__((ext_vector_type(4)))  unsigned short u16x4;

#define XCS 262144        // 64^3 x channel stride (f32)
#define OS  250047        // 63^3 out channel stride (f32)
#define SLAB_E 9216       // u16 per kd slab: [2 kh8][9 h][64 w][8 c]
#define KH8_E  4608       // 9*64*8
#define IMG_DW 536        // dwords per epilogue run slot (504 + 32 line pad)

__device__ __forceinline__ unsigned short f2bf(float f) {
    unsigned int u = __builtin_bit_cast(unsigned int, f);
    return (unsigned short)((u + 0x7fffu + ((u >> 16) & 1u)) >> 16);
}

__global__ __launch_bounds__(256, 4) void conv3d_k2_xcd(
    const float* __restrict__ x,
    const float* __restrict__ wgt,
    float* __restrict__ out)
{
    __shared__ __align__(16) unsigned char lds_raw[40960];
    unsigned short* tile  = (unsigned short*)lds_raw;            // [2][2][9][64][8] u16
    unsigned short* strip = (unsigned short*)(lds_raw + 36864);  // [2][16c][64w] u16
    float* img = (float*)lds_raw;                                 // [16][536] f32

    const int t   = threadIdx.x;
    const int l   = t & 63;
    const int wv  = t >> 6;        // wave 0..3
    const int col = l & 31;        // MFMA col (w) / A row (o)
    const int kh8 = l >> 5;        // k-half -> c8 group

    // XCD-partitioned decode: XCD (= bid%8 under round-robin) owns batch b.
    const int bid = blockIdx.x;
    const int b   = bid & 7;
    const int ht  = (bid >> 3) & 7;
    const int d   = bid >> 6;      // 0..62
    const int h0  = ht * 8;        // 8 output h rows

    // ---- A fragments: 64 contiguous floats per lane, compile-time shuffle ----
    short8 aF[8];
    {
        f32x4 wreg[16];
        const float* wp = wgt + col * 128 + kh8 * 64;
#pragma unroll
        for (int q = 0; q < 16; ++q) wreg[q] = *(const f32x4*)(wp + q * 4);
#pragma unroll
        for (int tap = 0; tap < 8; ++tap) {
            short8 a;
#pragma unroll
            for (int j = 0; j < 8; ++j) {
                const int k = j * 8 + tap;
                a[j] = (short)f2bf(wreg[k >> 2][k & 3]);
            }
            aF[tap] = a;
        }
    }

    // ---- staging: ONE 18x dwordx4 burst (both slabs), then LDS transpose ----
    const int cA   = t >> 4;       // c plane 0..15
    const int wq   = t & 15;       // 16-B w quad
    const int wB   = l;            // stage-B w
    const int kh8s = wv >> 1;
    const int half = wv & 1;

    f32x4 v[2][9];
#pragma unroll
    for (int p = 0; p < 2; ++p) {
        const float* xs = x + (size_t)b * 16 * XCS + (size_t)(d + p) * 4096
                            + (size_t)cA * XCS + wq * 4;
#pragma unroll
        for (int h = 0; h < 9; ++h) {
            int hp = h0 + h; if (hp > 63) hp = 63;
            v[p][h] = *(const f32x4*)(xs + hp * 64);
        }
    }

#pragma unroll
    for (int p = 0; p < 2; ++p) {
#pragma unroll
        for (int h = 0; h < 9; ++h) {
            unsigned short* sb = strip + (h & 1) * 1024;
            u16x4 pk;
#pragma unroll
            for (int i = 0; i < 4; ++i) pk[i] = f2bf(v[p][h][i]);
            *(u16x4*)&sb[cA * 64 + wq * 4] = pk;
            u16x4 q;
#pragma unroll
            for (int i = 0; i < 4; ++i)
                q[i] = sb[(wv * 4 + i) * 64 + wB];
            *(u16x4*)&tile[p * SLAB_E + kh8s * KH8_E + h * 512 + wB * 8 + half * 4] = q;
        }
    }
    __syncthreads();

    // ---- compute: 4 acc tiles (2 h-rows x 2 w-halves) kept in regs ----
    f32x16 acc[2][2];
#pragma unroll
    for (int th = 0; th < 2; ++th) {
        const int hl = wv * 2 + th;
#pragma unroll
        for (int wh = 0; wh < 2; ++wh) {
            const int wb = wh * 32;
            f32x16 a = {};
#pragma unroll
            for (int kd = 0; kd < 2; ++kd)
#pragma unroll
            for (int kh = 0; kh < 2; ++kh)
#pragma unroll
            for (int kw = 0; kw < 2; ++kw) {
                const int tap = kd * 4 + kh * 2 + kw;
                short8 bfrag = *(const short8*)&tile[kd * SLAB_E + kh8 * KH8_E
                    + (hl + kh) * 512 + (wb + col + kw) * 8];
                a = __builtin_amdgcn_mfma_f32_32x32x16_bf16(aF[tap], bfrag, a, 0, 0, 0);
            }
            acc[th][wh] = a;
        }
    }
    __syncthreads();   // done reading tile; LDS becomes the store image

    // ---- epilogue: 2 passes x 16 o-runs, line-aligned hybrid drain ----
    const int hvalid = (h0 == 56) ? 7 : 8;
    const int runlen = hvalid * 63;
#pragma unroll
    for (int p = 0; p < 2; ++p) {
        // scatter (y+1)^2 into img, shifted by each run's base&31 (128-B line)
#pragma unroll
        for (int th = 0; th < 2; ++th) {
            const int hl = wv * 2 + th;
            if (hl < hvalid) {
#pragma unroll
                for (int wh = 0; wh < 2; ++wh) {
                    const int wc = wh * 32 + col;
                    if (wc < 63) {
#pragma unroll
                        for (int r = 0; r < 8; ++r) {
                            const int rr = p * 8 + r;
                            const int og = (rr & 3) + 8 * (rr >> 2) + 4 * kh8;
                            const int ol = og - p * 16;
                            // base_dw mod 32: OS=-1, 3969=+1, 63=-1 (mod 32)
                            const int sh = (int)(((unsigned)(d - og - h0 + 1024)) & 31u);
                            float y = acc[th][wh][rr] + 1.0f;
                            img[ol * IMG_DW + sh + hl * 63 + wc] = y * y;
                        }
                    }
                }
            }
        }
        __syncthreads();
        // drain: wave wv owns 4 runs; cached fringes + NT line-aligned interior
#pragma unroll
        for (int orun = 0; orun < 4; ++orun) {
            const int ol = wv * 4 + orun;
            const int og = p * 16 + ol;
            const size_t base_dw = ((size_t)b * 32 + og) * (size_t)OS
                                 + (size_t)d * 3969 + (size_t)h0 * 63;
            float* gp = out + base_dw;
            const int sh = (int)(base_dw & 31);
            const float* ip = img + ol * IMG_DW + sh;
            int hc = (32 - sh) & 31;                 // head dwords (cached)
            if (hc > runlen) hc = runlen;
            if (l < hc) gp[l] = ip[l];
            const int ni = ((runlen - hc) >> 5) << 5; // interior (full 128-B lines)
            const int nv = ni >> 2;                   // x4 NT stores
#pragma unroll
            for (int rnd = 0; rnd < 2; ++rnd) {
                const int k = rnd * 64 + l;
                if (k < nv) {
                    f32x4 qv = *(const f32x4*)(ip + hc + 4 * k);
                    __builtin_nontemporal_store(qv, (f32x4*)(gp + hc + 4 * k));
                }
            }
            const int ts = hc + ni;                   // tail fringe (cached)
            if (ts + l < runlen) gp[ts + l] = ip[ts + l];
        }
        if (p == 0) __syncthreads();   // img reused by pass-1 scatter
    }
}

extern "C" void kernel_launch(void* const* d_in, const int* in_sizes, int n_in,
                              void* d_out, int out_size, void* d_ws, size_t ws_size,
                              hipStream_t stream) {
    const float* x   = (const float*)d_in[0];
    const float* wgt = (const float*)d_in[1];
    float* out = (float*)d_out;

    dim3 grid(4032);   // 1D; in-kernel decode partitions batches across XCDs
    dim3 block(256);
    conv3d_k2_xcd<<<grid, block, 0, stream>>>(x, wgt, out);
}

// Round 16
// 73.495 us; speedup vs baseline: 1.2603x; 1.0074x over previous
//
#include <hip/hip_runtime.h>
#include <hip/hip_bf16.h>

// 3D conv K=2 VALID + (y+1)^2, mfma_f32_32x32x16_bf16, vectorized streams.
// x: (8,16,64,64,64) f32; w: (32,128) f32, k = c*8 + kd*4 + kh*2 + kw.
// out: (8,32,63,63,63) f32.
//
// R15 (74.0 us) + ONE change: software-pipelined epilogue. The old 2-pass
// epilogue serialized {scatter, sync, drain, sync} and every sync emits
// s_waitcnt vmcnt(0) -> each NT store burst drained to DRAM while all waves
// waited. Now 4 passes x 8 o-runs with TWO disjoint img regions (A/B
// ping-pong, 17,152 B each, both overlaying the dead tile): per pass,
// scatter -> img[k&1]; sync; drain_k; scatter_{k+1} -> img[(k+1)&1] with NO
// intervening barrier (disjoint LDS) -> drain_k's stores retire under
// scatter_{k+1}'s VALU/LDS work. Same instruction count, same 5 barriers.
//   - XCD-partitioned decode (R15): b = bid&7 -> XCD b owns batch b
//   - staging: 18x dwordx4 fused burst + strip transpose (R12)
//   - tile [2kd][2kh8][9h][64w][8c] bf16, conflict-free b128 fragments
//   - line-aligned hybrid NT drain (R12)

typedef __attribute__((ext_vector_type(8)))  short short8;
typedef __attribute__((ext_vector_type(4)))  float f32x4;
typedef __attribute__((ext_vector_type(16))) float f32x16;
typedef __attribute__((ext_vector_type(4)))  unsigned short u16x4;

#define XCS 262144        // 64^3 x channel stride (f32)
#define OS  250047        // 63^3 out channel stride (f32)
#define SLAB_E 9216       // u16 per kd slab: [2 kh8][9 h][64 w][8 c]
#define KH8_E  4608       // 9*64*8
#define IMG_DW 536        // dwords per epilogue run slot (504 + 32 line pad)
#define IMG_B  17152      // bytes per img region: 8 runs x 536 x 4

__device__ __forceinline__ unsigned short f2bf(float f) {
    unsigned int u = __builtin_bit_cast(unsigned int, f);
    return (unsigned short)((u + 0x7fffu + ((u >> 16) & 1u)) >> 16);
}

__global__ __launch_bounds__(256, 4) void conv3d_k2_pipe(
    const float* __restrict__ x,
    const float* __restrict__ wgt,
    float* __restrict__ out)
{
    __shared__ __align__(16) unsigned char lds_raw[40960];
    unsigned short* tile  = (unsigned short*)lds_raw;            // [2][2][9][64][8] u16
    unsigned short* strip = (unsigned short*)(lds_raw + 36864);  // [2][16c][64w] u16
    float* imgA = (float*)lds_raw;                               // [8][536] f32
    float* imgB = (float*)(lds_raw + IMG_B);                     // [8][536] f32

    const int t   = threadIdx.x;
    const int l   = t & 63;
    const int wv  = t >> 6;        // wave 0..3
    const int col = l & 31;        // MFMA col (w) / A row (o)
    const int kh8 = l >> 5;        // k-half -> c8 group

    // XCD-partitioned decode: XCD (= bid%8 under round-robin) owns batch b.
    const int bid = blockIdx.x;
    const int b   = bid & 7;
    const int ht  = (bid >> 3) & 7;
    const int d   = bid >> 6;      // 0..62
    const int h0  = ht * 8;        // 8 output h rows

    // ---- A fragments: 64 contiguous floats per lane, compile-time shuffle ----
    short8 aF[8];
    {
        f32x4 wreg[16];
        const float* wp = wgt + col * 128 + kh8 * 64;
#pragma unroll
        for (int q = 0; q < 16; ++q) wreg[q] = *(const f32x4*)(wp + q * 4);
#pragma unroll
        for (int tap = 0; tap < 8; ++tap) {
            short8 a;
#pragma unroll
            for (int j = 0; j < 8; ++j) {
                const int k = j * 8 + tap;
                a[j] = (short)f2bf(wreg[k >> 2][k & 3]);
            }
            aF[tap] = a;
        }
    }

    // ---- staging: ONE 18x dwordx4 burst (both slabs), then LDS transpose ----
    const int cA   = t >> 4;       // c plane 0..15
    const int wq   = t & 15;       // 16-B w quad
    const int wB   = l;            // stage-B w
    const int kh8s = wv >> 1;
    const int half = wv & 1;

    f32x4 v[2][9];
#pragma unroll
    for (int p = 0; p < 2; ++p) {
        const float* xs = x + (size_t)b * 16 * XCS + (size_t)(d + p) * 4096
                            + (size_t)cA * XCS + wq * 4;
#pragma unroll
        for (int h = 0; h < 9; ++h) {
            int hp = h0 + h; if (hp > 63) hp = 63;
            v[p][h] = *(const f32x4*)(xs + hp * 64);
        }
    }

#pragma unroll
    for (int p = 0; p < 2; ++p) {
#pragma unroll
        for (int h = 0; h < 9; ++h) {
            unsigned short* sb = strip + (h & 1) * 1024;
            u16x4 pk;
#pragma unroll
            for (int i = 0; i < 4; ++i) pk[i] = f2bf(v[p][h][i]);
            *(u16x4*)&sb[cA * 64 + wq * 4] = pk;
            u16x4 q;
#pragma unroll
            for (int i = 0; i < 4; ++i)
                q[i] = sb[(wv * 4 + i) * 64 + wB];
            *(u16x4*)&tile[p * SLAB_E + kh8s * KH8_E + h * 512 + wB * 8 + half * 4] = q;
        }
    }
    __syncthreads();

    // ---- compute: 4 acc tiles (2 h-rows x 2 w-halves) kept in regs ----
    f32x16 acc[2][2];
#pragma unroll
    for (int th = 0; th < 2; ++th) {
        const int hl = wv * 2 + th;
#pragma unroll
        for (int wh = 0; wh < 2; ++wh) {
            const int wb = wh * 32;
            f32x16 a = {};
#pragma unroll
            for (int kd = 0; kd < 2; ++kd)
#pragma unroll
            for (int kh = 0; kh < 2; ++kh)
#pragma unroll
            for (int kw = 0; kw < 2; ++kw) {
                const int tap = kd * 4 + kh * 2 + kw;
                short8 bfrag = *(const short8*)&tile[kd * SLAB_E + kh8 * KH8_E
                    + (hl + kh) * 512 + (wb + col + kw) * 8];
                a = __builtin_amdgcn_mfma_f32_32x32x16_bf16(aF[tap], bfrag, a, 0, 0, 0);
            }
            acc[th][wh] = a;
        }
    }
    __syncthreads();   // tile reads done; img regions overlay the tile

    // ---- epilogue: 4 pipelined passes x 8 o-runs, A/B img ping-pong ----
    const int hvalid = (h0 == 56) ? 7 : 8;
    const int runlen = hvalid * 63;
#pragma unroll
    for (int pass = 0; pass < 4; ++pass) {
        float* img = (pass & 1) ? imgB : imgA;
        // scatter 8 o-planes of (y+1)^2, line-shift aligned (base&31)
#pragma unroll
        for (int th = 0; th < 2; ++th) {
            const int hl = wv * 2 + th;
            if (hl < hvalid) {
#pragma unroll
                for (int wh = 0; wh < 2; ++wh) {
                    const int wc = wh * 32 + col;
                    if (wc < 63) {
#pragma unroll
                        for (int r = 0; r < 4; ++r) {
                            const int rr = pass * 4 + r;
                            const int og = (rr & 3) + 8 * (rr >> 2) + 4 * kh8;
                            const int ol = og - pass * 8;
                            // base_dw mod 32: OS=-1, 3969=+1, 63=-1 (mod 32)
                            const int sh = (int)(((unsigned)(d - og - h0 + 1024)) & 31u);
                            float y = acc[th][wh][rr] + 1.0f;
                            img[ol * IMG_DW + sh + hl * 63 + wc] = y * y;
                        }
                    }
                }
            }
        }
        __syncthreads();
        // drain: wave wv owns 2 runs; cached fringes + NT line-aligned interior.
        // NO barrier after: next pass scatters into the OTHER img region, so
        // these NT stores retire under the next scatter's work.
#pragma unroll
        for (int orun = 0; orun < 2; ++orun) {
            const int ol = wv * 2 + orun;
            const int og = pass * 8 + ol;
            const size_t base_dw = ((size_t)b * 32 + og) * (size_t)OS
                                 + (size_t)d * 3969 + (size_t)h0 * 63;
            float* gp = out + base_dw;
            const int sh = (int)(base_dw & 31);
            const float* ip = img + ol * IMG_DW + sh;
            int hc = (32 - sh) & 31;                 // head dwords (cached)
            if (hc > runlen) hc = runlen;
            if (l < hc) gp[l] = ip[l];
            const int ni = ((runlen - hc) >> 5) << 5; // full 128-B lines
            const int nv = ni >> 2;                   // x4 NT stores
#pragma unroll
            for (int rnd = 0; rnd < 2; ++rnd) {
                const int k = rnd * 64 + l;
                if (k < nv) {
                    f32x4 qv = *(const f32x4*)(ip + hc + 4 * k);
                    __builtin_nontemporal_store(qv, (f32x4*)(gp + hc + 4 * k));
                }
            }
            const int ts = hc + ni;                   // tail fringe (cached)
            if (ts + l < runlen) gp[ts + l] = ip[ts + l];
        }
    }
}

extern "C" void kernel_launch(void* const* d_in, const int* in_sizes, int n_in,
                              void* d_out, int out_size, void* d_ws, size_t ws_size,
                              hipStream_t stream) {
    const float* x   = (const float*)d_in[0];
    const float* wgt = (const float*)d_in[1];
    float* out = (float*)d_out;

    dim3 grid(4032);   // 1D; in-kernel decode partitions batches across XCDs
    dim3 block(256);
    conv3d_k2_pipe<<<grid, block, 0, stream>>>(x, wgt, out);
}